// Round 16
// baseline (394.846 us; speedup 1.0000x reference)
//
#include <hip/hip_runtime.h>
#include <hip/hip_bf16.h>
#include <math.h>

// ---------------------------------------------------------------------------
// SelfAttn2d: out = x + gamma * (V @ softmax(Q K^T / sqrt(32))^T)
// B=4, C=256, N=4096, D=32.
// Round 16: fuse reduce_out into attn_part ("last block reduces"): after
// writing partials, each block fences + atomicAdd on a per-(b,mtile) counter;
// the 4th block acquires and does the x + gs*sum(O)/sum(L) epilogue for its
// 64m x 256e tile. Launches 3 -> 2 (+1KB memset). proj_sigma unchanged (R15).
// Deadlock-free: no spin waits, no co-residency assumptions.
// ---------------------------------------------------------------------------

#define NPOS 4096
#define XSTR 264   // bf16 row stride for 256-col LDS matrices (33*16B)

typedef __bf16 bf16x8 __attribute__((ext_vector_type(8)));
typedef float  f32x16 __attribute__((ext_vector_type(16)));

static __device__ inline unsigned int pk2(float a, float b) {
    union { __hip_bfloat16 h[2]; unsigned int u; } x;
    x.h[0] = __float2bfloat16(a);
    x.h[1] = __float2bfloat16(b);
    return x.u;
}
static __device__ inline bf16x8 cvt8(float4 a, float4 b) {
    union { bf16x8 v; unsigned int u[4]; } t;
    t.u[0] = pk2(a.x, a.y); t.u[1] = pk2(a.z, a.w);
    t.u[2] = pk2(b.x, b.y); t.u[3] = pk2(b.z, b.w);
    return t.v;
}
static __device__ inline float b2f(unsigned short u) {
    union { float f; unsigned int i; } x;
    x.i = ((unsigned int)u) << 16;
    return x.f;
}

// ---------------------------------------------------------------------------
// proj_sigma: grid (65, 4), 512 thr. (R15 verbatim)
//   blockIdx.x < 64 : proj path; blockIdx.x == 64: sigma path (y=0/1/2).
// ---------------------------------------------------------------------------
__global__ __launch_bounds__(512) void proj_sigma(const float* __restrict__ x,
                                                  const float* __restrict__ wq,
                                                  const float* __restrict__ wk,
                                                  const float* __restrict__ wv,
                                                  __hip_bfloat16* __restrict__ qT,
                                                  __hip_bfloat16* __restrict__ kT,
                                                  __hip_bfloat16* __restrict__ v,
                                                  float* __restrict__ scal) {
    __shared__ __align__(16) __hip_bfloat16 Wsh[256 * XSTR];  // 135 KB
    __shared__ float wred[16];
    __shared__ __align__(16) __hip_bfloat16 xb[2][256];

    int t = threadIdx.x;
    int wave = t >> 6, lane = t & 63, lo = lane & 31, hi = lane >> 5;

    if (blockIdx.x == 64) {
        int sb = blockIdx.y;
        if (sb == 3) return;

        if (sb < 2) {
            // ---- qk: 32x256, single-wave MFMA squaring chain (5 rounds) ----
            const float* w = (sb == 0) ? wq : wk;
            __hip_bfloat16* Wb = Wsh;
            __hip_bfloat16* As = Wsh + 32 * XSTR;
            float* xs = (float*)(Wsh + 32 * XSTR + 32 * 40);

            if (t < 256) {
                #pragma unroll
                for (int i = 0; i < 8; i++) {
                    int idx4 = t + 256 * i;
                    int row = idx4 >> 6, c4 = (idx4 & 63) * 4;
                    float4 w4 = *(const float4*)(w + (row << 8) + c4);
                    uint2 pk;
                    pk.x = pk2(w4.x, w4.y);
                    pk.y = pk2(w4.z, w4.w);
                    *(uint2*)&Wb[row * XSTR + c4] = pk;
                }
            }
            __syncthreads();

            if (wave == 0) {
                f32x16 c;
                #pragma unroll
                for (int r = 0; r < 16; r++) c[r] = 0.f;
                for (int kc = 0; kc < 16; kc++) {
                    bf16x8 af = *(const bf16x8*)&Wb[lo * XSTR + kc * 16 + hi * 8];
                    c = __builtin_amdgcn_mfma_f32_32x32x16_bf16(af, af, c, 0, 0, 0);
                }
                for (int sq = 0; sq < 5; sq++) {
                    float dsum = 0.f;
                    #pragma unroll
                    for (int r = 0; r < 16; r++) {
                        int row = (r & 3) + 8 * (r >> 2) + 4 * hi;
                        if (row == lo) dsum += c[r];
                    }
                    #pragma unroll
                    for (int m = 1; m <= 32; m <<= 1) dsum += __shfl_xor(dsum, m, 64);
                    float invt = 1.0f / dsum;
                    #pragma unroll
                    for (int g = 0; g < 4; g++) {
                        uint2 pk;
                        pk.x = pk2(c[4 * g + 0] * invt, c[4 * g + 1] * invt);
                        pk.y = pk2(c[4 * g + 2] * invt, c[4 * g + 3] * invt);
                        *(uint2*)&As[lo * 40 + 8 * g + 4 * hi] = pk;
                    }
                    __builtin_amdgcn_s_waitcnt(0);
                    bf16x8 a0 = *(const bf16x8*)&As[lo * 40 + hi * 8];
                    bf16x8 a1 = *(const bf16x8*)&As[lo * 40 + 16 + hi * 8];
                    #pragma unroll
                    for (int r = 0; r < 16; r++) c[r] = 0.f;
                    c = __builtin_amdgcn_mfma_f32_32x32x16_bf16(a0, a0, c, 0, 0, 0);
                    c = __builtin_amdgcn_mfma_f32_32x32x16_bf16(a1, a1, c, 0, 0, 0);
                }
                {
                    float dsum = 0.f;
                    #pragma unroll
                    for (int r = 0; r < 16; r++) {
                        int row = (r & 3) + 8 * (r >> 2) + 4 * hi;
                        if (row == lo) dsum += c[r];
                    }
                    #pragma unroll
                    for (int m = 1; m <= 32; m <<= 1) dsum += __shfl_xor(dsum, m, 64);
                    float invt = 1.0f / dsum;
                    #pragma unroll
                    for (int g = 0; g < 4; g++) {
                        uint2 pk;
                        pk.x = pk2(c[4 * g + 0] * invt, c[4 * g + 1] * invt);
                        pk.y = pk2(c[4 * g + 2] * invt, c[4 * g + 3] * invt);
                        *(uint2*)&As[lo * 40 + 8 * g + 4 * hi] = pk;
                    }
                    __builtin_amdgcn_s_waitcnt(0);
                }
                float xr = 1.0f + 0.01f * lo;
                for (int it = 0; it < 4; it++) {
                    float y = 0.f;
                    #pragma unroll 8
                    for (int j = 0; j < 32; j++) {
                        float xj = __shfl(xr, j, 64);
                        y += b2f(*(const unsigned short*)&As[lo * 40 + j]) * xj;
                    }
                    float ss = y * y;
                    #pragma unroll
                    for (int m = 1; m <= 16; m <<= 1) ss += __shfl_xor(ss, m, 64);
                    xr = y * rsqrtf(ss);
                }
                if (hi == 0) xs[lo] = xr;
            }
            __syncthreads();

            float z = 0.f;
            if (t < 256) {
                #pragma unroll 8
                for (int i = 0; i < 32; i++) z += w[i * 256 + t] * xs[i];
            }
            float zz = z * z;
            #pragma unroll
            for (int m = 1; m <= 32; m <<= 1) zz += __shfl_xor(zz, m, 64);
            if (lane == 0) wred[wave] = zz;
            __syncthreads();
            if (t == 0) {
                float lam = 0.f;
                for (int i = 0; i < 8; i++) lam += wred[i];
                scal[sb] = rsqrtf(lam);
            }
            return;
        }

        // ---- wv: 256x256 Gram^16 chain on MFMA (4 squarings) ----
        int p = wave >> 1;
        int q = wave & 1;

        #pragma unroll
        for (int i = 0; i < 32; i++) {
            int idx4 = t + 512 * i;
            int row = idx4 >> 6, c4 = (idx4 & 63) * 4;
            float4 w4 = *(const float4*)(wv + ((size_t)row << 8) + c4);
            uint2 pk;
            pk.x = pk2(w4.x, w4.y);
            pk.y = pk2(w4.z, w4.w);
            *(uint2*)&Wsh[row * XSTR + c4] = pk;
        }
        __syncthreads();

        for (int round = 0; round < 4; round++) {
            f32x16 c[2][4];
            #pragma unroll
            for (int mt = 0; mt < 2; mt++)
                #pragma unroll
                for (int j = 0; j < 4; j++)
                    #pragma unroll
                    for (int r = 0; r < 16; r++) c[mt][j][r] = 0.f;

            for (int kc = 0; kc < 16; kc++) {
                bf16x8 af[2], bfj[4];
                #pragma unroll
                for (int mt = 0; mt < 2; mt++)
                    af[mt] = *(const bf16x8*)&Wsh[((2 * p + mt) * 32 + lo) * XSTR + kc * 16 + hi * 8];
                #pragma unroll
                for (int j = 0; j < 4; j++)
                    bfj[j] = *(const bf16x8*)&Wsh[((4 * q + j) * 32 + lo) * XSTR + kc * 16 + hi * 8];
                #pragma unroll
                for (int mt = 0; mt < 2; mt++)
                    #pragma unroll
                    for (int j = 0; j < 4; j++)
                        c[mt][j] = __builtin_amdgcn_mfma_f32_32x32x16_bf16(af[mt], bfj[j], c[mt][j], 0, 0, 0);
            }

            float dsum = 0.f;
            #pragma unroll
            for (int mt = 0; mt < 2; mt++) {
                int Tm = 2 * p + mt;
                if ((Tm >> 2) == q) {
                    int j = Tm - 4 * q;
                    #pragma unroll
                    for (int r = 0; r < 16; r++) {
                        int row = (r & 3) + 8 * (r >> 2) + 4 * hi;
                        if (row == lo) dsum += c[mt][j][r];
                    }
                }
            }
            #pragma unroll
            for (int m = 1; m <= 32; m <<= 1) dsum += __shfl_xor(dsum, m, 64);
            if (lane == 0) wred[wave] = dsum;
            __syncthreads();
            float tr = 0.f;
            for (int i = 0; i < 8; i++) tr += wred[i];
            float invt = 1.0f / tr;

            #pragma unroll
            for (int mt = 0; mt < 2; mt++)
                #pragma unroll
                for (int j = 0; j < 4; j++) {
                    int base = ((4 * q + j) * 32 + lo) * XSTR + (2 * p + mt) * 32 + 4 * hi;
                    #pragma unroll
                    for (int g = 0; g < 4; g++) {
                        uint2 pk;
                        pk.x = pk2(c[mt][j][4 * g + 0] * invt, c[mt][j][4 * g + 1] * invt);
                        pk.y = pk2(c[mt][j][4 * g + 2] * invt, c[mt][j][4 * g + 3] * invt);
                        *(uint2*)&Wsh[base + 8 * g] = pk;
                    }
                }
            __syncthreads();
        }

        // ---- 4 power iterations via MFMA, A row-frags in registers ----
        bf16x8 af[16];
        #pragma unroll
        for (int kc = 0; kc < 16; kc++)
            af[kc] = *(const bf16x8*)&Wsh[(wave * 32 + lo) * XSTR + kc * 16 + hi * 8];

        if (t < 256) xb[0][t] = __float2bfloat16(1.0f + 0.01f * t);
        __syncthreads();

        for (int it = 0; it < 4; it++) {
            int cur = it & 1;
            f32x16 c;
            #pragma unroll
            for (int r = 0; r < 16; r++) c[r] = 0.f;
            #pragma unroll
            for (int kc = 0; kc < 16; kc++) {
                bf16x8 bfx = *(const bf16x8*)&xb[cur][kc * 16 + hi * 8];
                c = __builtin_amdgcn_mfma_f32_32x32x16_bf16(af[kc], bfx, c, 0, 0, 0);
            }
            if (lo == 0) {
                #pragma unroll
                for (int g = 0; g < 4; g++) {
                    uint2 pk;
                    pk.x = pk2(c[4 * g + 0], c[4 * g + 1]);
                    pk.y = pk2(c[4 * g + 2], c[4 * g + 3]);
                    *(uint2*)&xb[cur ^ 1][wave * 32 + 8 * g + 4 * hi] = pk;
                }
            }
            __syncthreads();
        }

        // ---- Rayleigh fp32 vs exact G (unroll 4 for load ILP) ----
        float z = 0.f, xt = 0.f;
        if (t < 256) {
            xt = b2f(*(const unsigned short*)&xb[0][t]);
            #pragma unroll 4
            for (int i = 0; i < 256; i++)
                z += wv[i * 256 + t] * b2f(*(const unsigned short*)&xb[0][i]);
        }
        float zz = z * z, ss = xt * xt;
        #pragma unroll
        for (int m = 1; m <= 32; m <<= 1) {
            zz += __shfl_xor(zz, m, 64);
            ss += __shfl_xor(ss, m, 64);
        }
        if (lane == 0) { wred[wave] = zz; wred[8 + wave] = ss; }
        __syncthreads();
        if (t == 0) {
            float ZZ = 0.f, SS = 0.f;
            for (int i = 0; i < 8; i++) { ZZ += wred[i]; SS += wred[8 + i]; }
            scal[2] = sqrtf(SS / ZZ);
        }
        return;
    }

    // ===================== proj path (unchanged logic) =====================
    __hip_bfloat16* XT  = Wsh;
    __hip_bfloat16* TqB = Wsh + 64 * XSTR;

    int n0 = blockIdx.x * 64;
    int b = blockIdx.y;
    const float* xb2 = x + ((size_t)b << 20);

    {
        int nl = t & 63, cg = t >> 6;
        #pragma unroll 8
        for (int i = 0; i < 32; i++) {
            int c = cg * 32 + i;
            XT[nl * XSTR + c] = __float2bfloat16(xb2[(size_t)c * NPOS + n0 + nl]);
        }
    }
    __syncthreads();

    f32x16 accv[2], accq;
    #pragma unroll
    for (int it = 0; it < 2; it++)
        #pragma unroll
        for (int r = 0; r < 16; r++) accv[it][r] = 0.f;
    #pragma unroll
    for (int r = 0; r < 16; r++) accq[r] = 0.f;

    const float* wvrow = wv + (size_t)(wave * 32 + lo) * 256 + hi * 8;
    const float* wqkrow = ((wave < 2) ? wq : wk) + (size_t)lo * 256 + hi * 8;
    int qk_it = wave & 1;

    for (int kc = 0; kc < 16; kc++) {
        bf16x8 af0 = *(const bf16x8*)&XT[lo * XSTR + kc * 16 + hi * 8];
        bf16x8 af1 = *(const bf16x8*)&XT[(32 + lo) * XSTR + kc * 16 + hi * 8];
        float4 wa = *(const float4*)(wvrow + kc * 16);
        float4 wb = *(const float4*)(wvrow + kc * 16 + 4);
        bf16x8 bfv = cvt8(wa, wb);
        accv[0] = __builtin_amdgcn_mfma_f32_32x32x16_bf16(af0, bfv, accv[0], 0, 0, 0);
        accv[1] = __builtin_amdgcn_mfma_f32_32x32x16_bf16(af1, bfv, accv[1], 0, 0, 0);
        if (wave < 4) {
            float4 qa = *(const float4*)(wqkrow + kc * 16);
            float4 qb = *(const float4*)(wqkrow + kc * 16 + 4);
            bf16x8 bfq = cvt8(qa, qb);
            accq = __builtin_amdgcn_mfma_f32_32x32x16_bf16(qk_it ? af1 : af0, bfq, accq, 0, 0, 0);
        }
    }

    __hip_bfloat16* vbb = v + ((size_t)b << 20) + (size_t)(wave * 32 + lo) * NPOS + n0;
    #pragma unroll
    for (int it = 0; it < 2; it++)
        #pragma unroll
        for (int g = 0; g < 4; g++) {
            uint2 pk;
            pk.x = pk2(accv[it][4 * g + 0], accv[it][4 * g + 1]);
            pk.y = pk2(accv[it][4 * g + 2], accv[it][4 * g + 3]);
            *(uint2*)(vbb + it * 32 + 8 * g + 4 * hi) = pk;
        }

    if (wave < 4) {
        __hip_bfloat16* T = TqB + wave * (32 * 40);
        #pragma unroll
        for (int r = 0; r < 16; r++) {
            int n = (r & 3) + 8 * (r >> 2) + 4 * hi;
            T[n * 40 + lo] = __float2bfloat16(accq[r]);
        }
    }
    __syncthreads();
    if (wave < 4) {
        __hip_bfloat16* T = TqB + wave * (32 * 40);
        __hip_bfloat16* dst = ((wave < 2) ? qT : kT) + ((size_t)b << 17)
                              + (size_t)(n0 + qk_it * 32) * 32;
        #pragma unroll
        for (int p = 0; p < 2; p++) {
            int idx = p * 64 + lane;
            int n = idx >> 2, quad = idx & 3;
            bf16x8 row = *(const bf16x8*)&T[n * 40 + quad * 8];
            *(bf16x8*)(dst + (size_t)n * 32 + quad * 8) = row;
        }
    }
}

// ---------------------------------------------------------------------------
// attn_part: R13/R15 hot loop verbatim + fused "last block reduces" epilogue.
// 256 thr, grid 1024 (= 4 b x 64 m-tiles x 4 n-quarters), 8x2 phases of 64 n.
// ---------------------------------------------------------------------------
__global__ __launch_bounds__(256) void attn_part(const float* __restrict__ x,
                                                 const __hip_bfloat16* __restrict__ qT,
                                                 const __hip_bfloat16* __restrict__ kT,
                                                 const __hip_bfloat16* __restrict__ v,
                                                 const float* __restrict__ scal,
                                                 const float* __restrict__ gam,
                                                 __hip_bfloat16* __restrict__ Opart,
                                                 float* __restrict__ Lsum,
                                                 int* __restrict__ cnt,
                                                 float* __restrict__ out) {
    __shared__ __hip_bfloat16 Plds0[64 * 72];
    __shared__ __hip_bfloat16 Plds1[64 * 72];
    __shared__ float Lp[4][32];
    __shared__ float LtotS[64];
    __shared__ int lastFlag;

    int t = threadIdx.x;
    int wave = t >> 6, lane = t & 63;
    int lo = lane & 31, hi = lane >> 5;

    int blk = blockIdx.x;
    int x8 = blk & 7;
    int b = x8 >> 1;
    int nq = (blk >> 3) & 3;
    int m0 = (((x8 & 1) << 5) + (blk >> 5)) << 6;
    int nbase = nq << 10;

    const __hip_bfloat16* qTb = qT + ((size_t)b << 17);
    const __hip_bfloat16* kTb = kT + ((size_t)b << 17);
    const __hip_bfloat16* vb  = v  + ((size_t)b << 20);

    int mtile_s = wave >> 1, ntile_s = wave & 1;
    int e0w = wave << 6;
    float qkscale = scal[0] * scal[1] * 0.17677669529663687f;

    bf16x8 qf0 = *(const bf16x8*)(qTb + ((size_t)(m0 + mtile_s * 32 + lo)) * 32 + 0  + hi * 8);
    bf16x8 qf1 = *(const bf16x8*)(qTb + ((size_t)(m0 + mtile_s * 32 + lo)) * 32 + 16 + hi * 8);

    f32x16 acc[2][2];
    #pragma unroll
    for (int et = 0; et < 2; et++)
        #pragma unroll
        for (int mt = 0; mt < 2; mt++)
            #pragma unroll
            for (int r = 0; r < 16; r++) acc[et][mt][r] = 0.f;
    float l_acc = 0.f;

    const __hip_bfloat16* krow0 = kTb + (size_t)(ntile_s * 32 + lo) * 32 + hi * 8;
    const __hip_bfloat16* va0b = vb + (size_t)(e0w + lo) * NPOS + hi * 8;
    const __hip_bfloat16* va1b = vb + (size_t)(e0w + 32 + lo) * NPOS + hi * 8;
    int mrow = mtile_s * 32 + lo;
    int nloc0 = ntile_s * 32 + 4 * hi;

    bf16x8 kfA0, kfA1, kfB0, kfB1;
    {
        const __hip_bfloat16* ka = krow0 + (size_t)nbase * 32;
        kfA0 = *(const bf16x8*)(ka);
        kfA1 = *(const bf16x8*)(ka + 16);
    }

    for (int ss = 0; ss < 8; ss++) {
        int n0 = nbase + 128 * ss;

        // phase A
        {
            f32x16 sv;
            #pragma unroll
            for (int r = 0; r < 16; r++) sv[r] = 0.f;
            sv = __builtin_amdgcn_mfma_f32_32x32x16_bf16(kfA0, qf0, sv, 0, 0, 0);
            sv = __builtin_amdgcn_mfma_f32_32x32x16_bf16(kfA1, qf1, sv, 0, 0, 0);

            const __hip_bfloat16* ka = krow0 + (size_t)(n0 + 64) * 32;
            kfB0 = *(const bf16x8*)(ka);
            kfB1 = *(const bf16x8*)(ka + 16);

            #pragma unroll
            for (int g = 0; g < 4; g++) {
                float p0 = __expf(sv[4 * g + 0] * qkscale);
                float p1 = __expf(sv[4 * g + 1] * qkscale);
                float p2 = __expf(sv[4 * g + 2] * qkscale);
                float p3 = __expf(sv[4 * g + 3] * qkscale);
                l_acc += (p0 + p1) + (p2 + p3);
                uint2 pk;
                pk.x = pk2(p0, p1);
                pk.y = pk2(p2, p3);
                *(uint2*)(&Plds0[mrow * 72 + nloc0 + 8 * g]) = pk;
            }
            __syncthreads();

            #pragma unroll
            for (int kc = 0; kc < 4; kc++) {
                bf16x8 pf0 = *(const bf16x8*)(&Plds0[(lo)      * 72 + kc * 16 + hi * 8]);
                bf16x8 pf1 = *(const bf16x8*)(&Plds0[(32 + lo) * 72 + kc * 16 + hi * 8]);
                bf16x8 vf0 = *(const bf16x8*)(va0b + n0 + kc * 16);
                bf16x8 vf1 = *(const bf16x8*)(va1b + n0 + kc * 16);
                acc[0][0] = __builtin_amdgcn_mfma_f32_32x32x16_bf16(vf0, pf0, acc[0][0], 0, 0, 0);
                acc[0][1] = __builtin_amdgcn_mfma_f32_32x32x16_bf16(vf0, pf1, acc[0][1], 0, 0, 0);
                acc[1][0] = __builtin_amdgcn_mfma_f32_32x32x16_bf16(vf1, pf0, acc[1][0], 0, 0, 0);
                acc[1][1] = __builtin_amdgcn_mfma_f32_32x32x16_bf16(vf1, pf1, acc[1][1], 0, 0, 0);
            }
        }

        // phase B
        {
            int n1 = n0 + 64;
            f32x16 sv;
            #pragma unroll
            for (int r = 0; r < 16; r++) sv[r] = 0.f;
            sv = __builtin_amdgcn_mfma_f32_32x32x16_bf16(kfB0, qf0, sv, 0, 0, 0);
            sv = __builtin_amdgcn_mfma_f32_32x32x16_bf16(kfB1, qf1, sv, 0, 0, 0);

            if (ss < 7) {
                const __hip_bfloat16* ka = krow0 + (size_t)(n1 + 64) * 32;
                kfA0 = *(const bf16x8*)(ka);
                kfA1 = *(const bf16x8*)(ka + 16);
            }

            #pragma unroll
            for (int g = 0; g < 4; g++) {
                float p0 = __expf(sv[4 * g + 0] * qkscale);
                float p1 = __expf(sv[4 * g + 1] * qkscale);
                float p2 = __expf(sv[4 * g + 2] * qkscale);
                float p3 = __expf(sv[4 * g + 3] * qkscale);
                l_acc += (p0 + p1) + (p2 + p3);
                uint2 pk;
                pk.x = pk2(p0, p1);
                pk.y = pk2(p2, p3);
                *(uint2*)(&Plds1[mrow * 72 + nloc0 + 8 * g]) = pk;
            }
            __syncthreads();

            #pragma unroll
            for (int kc = 0; kc < 4; kc++) {
                bf16x8 pf0 = *(const bf16x8*)(&Plds1[(lo)      * 72 + kc * 16 + hi * 8]);
                bf16x8 pf1 = *(const bf16x8*)(&Plds1[(32 + lo) * 72 + kc * 16 + hi * 8]);
                bf16x8 vf0 = *(const bf16x8*)(va0b + n1 + kc * 16);
                bf16x8 vf1 = *(const bf16x8*)(va1b + n1 + kc * 16);
                acc[0][0] = __builtin_amdgcn_mfma_f32_32x32x16_bf16(vf0, pf0, acc[0][0], 0, 0, 0);
                acc[0][1] = __builtin_amdgcn_mfma_f32_32x32x16_bf16(vf0, pf1, acc[0][1], 0, 0, 0);
                acc[1][0] = __builtin_amdgcn_mfma_f32_32x32x16_bf16(vf1, pf0, acc[1][0], 0, 0, 0);
                acc[1][1] = __builtin_amdgcn_mfma_f32_32x32x16_bf16(vf1, pf1, acc[1][1], 0, 0, 0);
            }
        }
    }

    float lsum = l_acc + __shfl_xor(l_acc, 32, 64);
    if (lane < 32) Lp[wave][lane] = lsum;
    __syncthreads();
    if (wave == 0) {
        int l2 = lane & 31;
        float Lv = (lane < 32) ? (Lp[0][l2] + Lp[1][l2]) : (Lp[2][l2] + Lp[3][l2]);
        Lsum[(size_t)(nq * 4 + b) * NPOS + m0 + ((lane >> 5) << 5) + l2] = Lv;
    }

    __hip_bfloat16* Ob = Opart + ((size_t)(nq * 4 + b) << 20);
    #pragma unroll
    for (int mt = 0; mt < 2; mt++) {
        int m = m0 + mt * 32 + lo;
        #pragma unroll
        for (int et = 0; et < 2; et++) {
            #pragma unroll
            for (int r = 0; r < 16; r++) {
                int e = e0w + et * 32 + (r & 3) + 8 * (r >> 2) + 4 * hi;
                Ob[(size_t)e * NPOS + m] = __float2bfloat16(acc[et][mt][r]);
            }
        }
    }

    // ---- fused reduce: last of the 4 nq-blocks for (b, m0) does epilogue ----
    __threadfence();   // release: partials visible device-wide
    if (t == 0) {
        int prev = atomicAdd(&cnt[(b << 6) + (m0 >> 6)], 1);
        lastFlag = (prev == 3);
    }
    __syncthreads();
    if (!lastFlag) return;
    __threadfence();   // acquire: see other blocks' partials

    float gs = gam[0] * scal[2];
    if (t < 64) {
        float Ltot = 0.f;
        #pragma unroll
        for (int qq = 0; qq < 4; qq++)
            Ltot += Lsum[(size_t)(qq * 4 + b) * NPOS + m0 + t];
        LtotS[t] = gs / Ltot;
    }
    __syncthreads();

    // thread t -> m-quad (t&15)*4, e = (t>>4) + 16k
    int m4 = (t & 15) * 4;
    int eb = t >> 4;
    const float* xb3 = x + ((size_t)b << 20);
    float* ob2 = out + ((size_t)b << 20);
    float f0 = LtotS[m4], f1 = LtotS[m4 + 1], f2 = LtotS[m4 + 2], f3 = LtotS[m4 + 3];
    for (int e = eb; e < 256; e += 16) {
        size_t off = (size_t)e * NPOS + m0 + m4;
        float4 xv = *(const float4*)(xb3 + off);
        float o0 = 0.f, o1 = 0.f, o2 = 0.f, o3 = 0.f;
        #pragma unroll
        for (int qq = 0; qq < 4; qq++) {
            ushort4 a = *(const ushort4*)(Opart + ((size_t)(qq * 4 + b) << 20) + off);
            o0 += b2f(a.x); o1 += b2f(a.y); o2 += b2f(a.z); o3 += b2f(a.w);
        }
        float4 r;
        r.x = xv.x + f0 * o0;
        r.y = xv.y + f1 * o1;
        r.z = xv.z + f2 * o2;
        r.w = xv.w + f3 * o3;
        *(float4*)(ob2 + off) = r;
    }
}

// ---------------------------------------------------------------------------
extern "C" void kernel_launch(void* const* d_in, const int* in_sizes, int n_in,
                              void* d_out, int out_size, void* d_ws, size_t ws_size,
                              hipStream_t stream) {
    const float* x     = (const float*)d_in[0];
    const float* wq    = (const float*)d_in[1];
    const float* wk    = (const float*)d_in[2];
    const float* wv    = (const float*)d_in[3];
    const float* gamma = (const float*)d_in[4];
    float* out = (float*)d_out;

    char* wsb = (char*)d_ws;
    float* scal = (float*)wsb;                           // 256 B
    __hip_bfloat16* qT = (__hip_bfloat16*)(wsb + 256);   // 1 MB
    __hip_bfloat16* kT = qT + ((size_t)4 << 17);         // 1 MB
    __hip_bfloat16* vp = kT + ((size_t)4 << 17);         // 8 MB
    __hip_bfloat16* Opart = vp + ((size_t)4 << 20);      // 32 MB (16 slices x 2MB)
    float* Lsum = (float*)(Opart + ((size_t)16 << 20));  // 256 KB
    int* cnt = (int*)(Lsum + 65536);                     // 1 KB (256 counters)

    hipMemsetAsync(cnt, 0, 256 * sizeof(int), stream);
    proj_sigma<<<dim3(65, 4), 512, 0, stream>>>(x, wq, wk, wv, qT, kT, vp, scal);
    attn_part<<<1024, 256, 0, stream>>>(x, qT, kT, vp, scal, gamma, Opart, Lsum, cnt, out);
}

// Round 17
// 223.968 us; speedup vs baseline: 1.7630x; 1.7630x over previous
//
#include <hip/hip_runtime.h>
#include <hip/hip_bf16.h>
#include <math.h>

// ---------------------------------------------------------------------------
// SelfAttn2d: out = x + gamma * (V @ softmax(Q K^T / sqrt(32))^T)
// B=4, C=256, N=4096, D=32.
// Round 17: revert R16's fused epilogue (device-fence + cross-XCD partial
// reads regressed attn 88->251). Back to R15 3-launch structure. One change:
// attn_part hoists the va0b V-row loads of each phase to just after the
// S-MFMA (static names vp0..3) so their L2 latency hides under
// exp+pack+barrier; va1b loads stay inline and overlap the vp MFMAs.
// ---------------------------------------------------------------------------

#define NPOS 4096
#define XSTR 264   // bf16 row stride for 256-col LDS matrices (33*16B)

typedef __bf16 bf16x8 __attribute__((ext_vector_type(8)));
typedef float  f32x16 __attribute__((ext_vector_type(16)));

static __device__ inline unsigned int pk2(float a, float b) {
    union { __hip_bfloat16 h[2]; unsigned int u; } x;
    x.h[0] = __float2bfloat16(a);
    x.h[1] = __float2bfloat16(b);
    return x.u;
}
static __device__ inline bf16x8 cvt8(float4 a, float4 b) {
    union { bf16x8 v; unsigned int u[4]; } t;
    t.u[0] = pk2(a.x, a.y); t.u[1] = pk2(a.z, a.w);
    t.u[2] = pk2(b.x, b.y); t.u[3] = pk2(b.z, b.w);
    return t.v;
}
static __device__ inline float b2f(unsigned short u) {
    union { float f; unsigned int i; } x;
    x.i = ((unsigned int)u) << 16;
    return x.f;
}

// ---------------------------------------------------------------------------
// proj_sigma: grid (65, 4), 512 thr. (R15 verbatim)
//   blockIdx.x < 64 : proj path; blockIdx.x == 64: sigma path (y=0/1/2).
// ---------------------------------------------------------------------------
__global__ __launch_bounds__(512) void proj_sigma(const float* __restrict__ x,
                                                  const float* __restrict__ wq,
                                                  const float* __restrict__ wk,
                                                  const float* __restrict__ wv,
                                                  __hip_bfloat16* __restrict__ qT,
                                                  __hip_bfloat16* __restrict__ kT,
                                                  __hip_bfloat16* __restrict__ v,
                                                  float* __restrict__ scal) {
    __shared__ __align__(16) __hip_bfloat16 Wsh[256 * XSTR];  // 135 KB
    __shared__ float wred[16];
    __shared__ __align__(16) __hip_bfloat16 xb[2][256];

    int t = threadIdx.x;
    int wave = t >> 6, lane = t & 63, lo = lane & 31, hi = lane >> 5;

    if (blockIdx.x == 64) {
        int sb = blockIdx.y;
        if (sb == 3) return;

        if (sb < 2) {
            // ---- qk: 32x256, single-wave MFMA squaring chain (5 rounds) ----
            const float* w = (sb == 0) ? wq : wk;
            __hip_bfloat16* Wb = Wsh;
            __hip_bfloat16* As = Wsh + 32 * XSTR;
            float* xs = (float*)(Wsh + 32 * XSTR + 32 * 40);

            if (t < 256) {
                #pragma unroll
                for (int i = 0; i < 8; i++) {
                    int idx4 = t + 256 * i;
                    int row = idx4 >> 6, c4 = (idx4 & 63) * 4;
                    float4 w4 = *(const float4*)(w + (row << 8) + c4);
                    uint2 pk;
                    pk.x = pk2(w4.x, w4.y);
                    pk.y = pk2(w4.z, w4.w);
                    *(uint2*)&Wb[row * XSTR + c4] = pk;
                }
            }
            __syncthreads();

            if (wave == 0) {
                f32x16 c;
                #pragma unroll
                for (int r = 0; r < 16; r++) c[r] = 0.f;
                for (int kc = 0; kc < 16; kc++) {
                    bf16x8 af = *(const bf16x8*)&Wb[lo * XSTR + kc * 16 + hi * 8];
                    c = __builtin_amdgcn_mfma_f32_32x32x16_bf16(af, af, c, 0, 0, 0);
                }
                for (int sq = 0; sq < 5; sq++) {
                    float dsum = 0.f;
                    #pragma unroll
                    for (int r = 0; r < 16; r++) {
                        int row = (r & 3) + 8 * (r >> 2) + 4 * hi;
                        if (row == lo) dsum += c[r];
                    }
                    #pragma unroll
                    for (int m = 1; m <= 32; m <<= 1) dsum += __shfl_xor(dsum, m, 64);
                    float invt = 1.0f / dsum;
                    #pragma unroll
                    for (int g = 0; g < 4; g++) {
                        uint2 pk;
                        pk.x = pk2(c[4 * g + 0] * invt, c[4 * g + 1] * invt);
                        pk.y = pk2(c[4 * g + 2] * invt, c[4 * g + 3] * invt);
                        *(uint2*)&As[lo * 40 + 8 * g + 4 * hi] = pk;
                    }
                    __builtin_amdgcn_s_waitcnt(0);
                    bf16x8 a0 = *(const bf16x8*)&As[lo * 40 + hi * 8];
                    bf16x8 a1 = *(const bf16x8*)&As[lo * 40 + 16 + hi * 8];
                    #pragma unroll
                    for (int r = 0; r < 16; r++) c[r] = 0.f;
                    c = __builtin_amdgcn_mfma_f32_32x32x16_bf16(a0, a0, c, 0, 0, 0);
                    c = __builtin_amdgcn_mfma_f32_32x32x16_bf16(a1, a1, c, 0, 0, 0);
                }
                {
                    float dsum = 0.f;
                    #pragma unroll
                    for (int r = 0; r < 16; r++) {
                        int row = (r & 3) + 8 * (r >> 2) + 4 * hi;
                        if (row == lo) dsum += c[r];
                    }
                    #pragma unroll
                    for (int m = 1; m <= 32; m <<= 1) dsum += __shfl_xor(dsum, m, 64);
                    float invt = 1.0f / dsum;
                    #pragma unroll
                    for (int g = 0; g < 4; g++) {
                        uint2 pk;
                        pk.x = pk2(c[4 * g + 0] * invt, c[4 * g + 1] * invt);
                        pk.y = pk2(c[4 * g + 2] * invt, c[4 * g + 3] * invt);
                        *(uint2*)&As[lo * 40 + 8 * g + 4 * hi] = pk;
                    }
                    __builtin_amdgcn_s_waitcnt(0);
                }
                float xr = 1.0f + 0.01f * lo;
                for (int it = 0; it < 4; it++) {
                    float y = 0.f;
                    #pragma unroll 8
                    for (int j = 0; j < 32; j++) {
                        float xj = __shfl(xr, j, 64);
                        y += b2f(*(const unsigned short*)&As[lo * 40 + j]) * xj;
                    }
                    float ss = y * y;
                    #pragma unroll
                    for (int m = 1; m <= 16; m <<= 1) ss += __shfl_xor(ss, m, 64);
                    xr = y * rsqrtf(ss);
                }
                if (hi == 0) xs[lo] = xr;
            }
            __syncthreads();

            float z = 0.f;
            if (t < 256) {
                #pragma unroll 8
                for (int i = 0; i < 32; i++) z += w[i * 256 + t] * xs[i];
            }
            float zz = z * z;
            #pragma unroll
            for (int m = 1; m <= 32; m <<= 1) zz += __shfl_xor(zz, m, 64);
            if (lane == 0) wred[wave] = zz;
            __syncthreads();
            if (t == 0) {
                float lam = 0.f;
                for (int i = 0; i < 8; i++) lam += wred[i];
                scal[sb] = rsqrtf(lam);
            }
            return;
        }

        // ---- wv: 256x256 Gram^16 chain on MFMA (4 squarings) ----
        int p = wave >> 1;
        int q = wave & 1;

        #pragma unroll
        for (int i = 0; i < 32; i++) {
            int idx4 = t + 512 * i;
            int row = idx4 >> 6, c4 = (idx4 & 63) * 4;
            float4 w4 = *(const float4*)(wv + ((size_t)row << 8) + c4);
            uint2 pk;
            pk.x = pk2(w4.x, w4.y);
            pk.y = pk2(w4.z, w4.w);
            *(uint2*)&Wsh[row * XSTR + c4] = pk;
        }
        __syncthreads();

        for (int round = 0; round < 4; round++) {
            f32x16 c[2][4];
            #pragma unroll
            for (int mt = 0; mt < 2; mt++)
                #pragma unroll
                for (int j = 0; j < 4; j++)
                    #pragma unroll
                    for (int r = 0; r < 16; r++) c[mt][j][r] = 0.f;

            for (int kc = 0; kc < 16; kc++) {
                bf16x8 af[2], bfj[4];
                #pragma unroll
                for (int mt = 0; mt < 2; mt++)
                    af[mt] = *(const bf16x8*)&Wsh[((2 * p + mt) * 32 + lo) * XSTR + kc * 16 + hi * 8];
                #pragma unroll
                for (int j = 0; j < 4; j++)
                    bfj[j] = *(const bf16x8*)&Wsh[((4 * q + j) * 32 + lo) * XSTR + kc * 16 + hi * 8];
                #pragma unroll
                for (int mt = 0; mt < 2; mt++)
                    #pragma unroll
                    for (int j = 0; j < 4; j++)
                        c[mt][j] = __builtin_amdgcn_mfma_f32_32x32x16_bf16(af[mt], bfj[j], c[mt][j], 0, 0, 0);
            }

            float dsum = 0.f;
            #pragma unroll
            for (int mt = 0; mt < 2; mt++) {
                int Tm = 2 * p + mt;
                if ((Tm >> 2) == q) {
                    int j = Tm - 4 * q;
                    #pragma unroll
                    for (int r = 0; r < 16; r++) {
                        int row = (r & 3) + 8 * (r >> 2) + 4 * hi;
                        if (row == lo) dsum += c[mt][j][r];
                    }
                }
            }
            #pragma unroll
            for (int m = 1; m <= 32; m <<= 1) dsum += __shfl_xor(dsum, m, 64);
            if (lane == 0) wred[wave] = dsum;
            __syncthreads();
            float tr = 0.f;
            for (int i = 0; i < 8; i++) tr += wred[i];
            float invt = 1.0f / tr;

            #pragma unroll
            for (int mt = 0; mt < 2; mt++)
                #pragma unroll
                for (int j = 0; j < 4; j++) {
                    int base = ((4 * q + j) * 32 + lo) * XSTR + (2 * p + mt) * 32 + 4 * hi;
                    #pragma unroll
                    for (int g = 0; g < 4; g++) {
                        uint2 pk;
                        pk.x = pk2(c[mt][j][4 * g + 0] * invt, c[mt][j][4 * g + 1] * invt);
                        pk.y = pk2(c[mt][j][4 * g + 2] * invt, c[mt][j][4 * g + 3] * invt);
                        *(uint2*)&Wsh[base + 8 * g] = pk;
                    }
                }
            __syncthreads();
        }

        // ---- 4 power iterations via MFMA, A row-frags in registers ----
        bf16x8 af[16];
        #pragma unroll
        for (int kc = 0; kc < 16; kc++)
            af[kc] = *(const bf16x8*)&Wsh[(wave * 32 + lo) * XSTR + kc * 16 + hi * 8];

        if (t < 256) xb[0][t] = __float2bfloat16(1.0f + 0.01f * t);
        __syncthreads();

        for (int it = 0; it < 4; it++) {
            int cur = it & 1;
            f32x16 c;
            #pragma unroll
            for (int r = 0; r < 16; r++) c[r] = 0.f;
            #pragma unroll
            for (int kc = 0; kc < 16; kc++) {
                bf16x8 bfx = *(const bf16x8*)&xb[cur][kc * 16 + hi * 8];
                c = __builtin_amdgcn_mfma_f32_32x32x16_bf16(af[kc], bfx, c, 0, 0, 0);
            }
            if (lo == 0) {
                #pragma unroll
                for (int g = 0; g < 4; g++) {
                    uint2 pk;
                    pk.x = pk2(c[4 * g + 0], c[4 * g + 1]);
                    pk.y = pk2(c[4 * g + 2], c[4 * g + 3]);
                    *(uint2*)&xb[cur ^ 1][wave * 32 + 8 * g + 4 * hi] = pk;
                }
            }
            __syncthreads();
        }

        // ---- Rayleigh fp32 vs exact G (unroll 4 for load ILP) ----
        float z = 0.f, xt = 0.f;
        if (t < 256) {
            xt = b2f(*(const unsigned short*)&xb[0][t]);
            #pragma unroll 4
            for (int i = 0; i < 256; i++)
                z += wv[i * 256 + t] * b2f(*(const unsigned short*)&xb[0][i]);
        }
        float zz = z * z, ss = xt * xt;
        #pragma unroll
        for (int m = 1; m <= 32; m <<= 1) {
            zz += __shfl_xor(zz, m, 64);
            ss += __shfl_xor(ss, m, 64);
        }
        if (lane == 0) { wred[wave] = zz; wred[8 + wave] = ss; }
        __syncthreads();
        if (t == 0) {
            float ZZ = 0.f, SS = 0.f;
            for (int i = 0; i < 8; i++) { ZZ += wred[i]; SS += wred[8 + i]; }
            scal[2] = sqrtf(SS / ZZ);
        }
        return;
    }

    // ===================== proj path (unchanged logic) =====================
    __hip_bfloat16* XT  = Wsh;
    __hip_bfloat16* TqB = Wsh + 64 * XSTR;

    int n0 = blockIdx.x * 64;
    int b = blockIdx.y;
    const float* xb2 = x + ((size_t)b << 20);

    {
        int nl = t & 63, cg = t >> 6;
        #pragma unroll 8
        for (int i = 0; i < 32; i++) {
            int c = cg * 32 + i;
            XT[nl * XSTR + c] = __float2bfloat16(xb2[(size_t)c * NPOS + n0 + nl]);
        }
    }
    __syncthreads();

    f32x16 accv[2], accq;
    #pragma unroll
    for (int it = 0; it < 2; it++)
        #pragma unroll
        for (int r = 0; r < 16; r++) accv[it][r] = 0.f;
    #pragma unroll
    for (int r = 0; r < 16; r++) accq[r] = 0.f;

    const float* wvrow = wv + (size_t)(wave * 32 + lo) * 256 + hi * 8;
    const float* wqkrow = ((wave < 2) ? wq : wk) + (size_t)lo * 256 + hi * 8;
    int qk_it = wave & 1;

    for (int kc = 0; kc < 16; kc++) {
        bf16x8 af0 = *(const bf16x8*)&XT[lo * XSTR + kc * 16 + hi * 8];
        bf16x8 af1 = *(const bf16x8*)&XT[(32 + lo) * XSTR + kc * 16 + hi * 8];
        float4 wa = *(const float4*)(wvrow + kc * 16);
        float4 wb = *(const float4*)(wvrow + kc * 16 + 4);
        bf16x8 bfv = cvt8(wa, wb);
        accv[0] = __builtin_amdgcn_mfma_f32_32x32x16_bf16(af0, bfv, accv[0], 0, 0, 0);
        accv[1] = __builtin_amdgcn_mfma_f32_32x32x16_bf16(af1, bfv, accv[1], 0, 0, 0);
        if (wave < 4) {
            float4 qa = *(const float4*)(wqkrow + kc * 16);
            float4 qb = *(const float4*)(wqkrow + kc * 16 + 4);
            bf16x8 bfq = cvt8(qa, qb);
            accq = __builtin_amdgcn_mfma_f32_32x32x16_bf16(qk_it ? af1 : af0, bfq, accq, 0, 0, 0);
        }
    }

    __hip_bfloat16* vbb = v + ((size_t)b << 20) + (size_t)(wave * 32 + lo) * NPOS + n0;
    #pragma unroll
    for (int it = 0; it < 2; it++)
        #pragma unroll
        for (int g = 0; g < 4; g++) {
            uint2 pk;
            pk.x = pk2(accv[it][4 * g + 0], accv[it][4 * g + 1]);
            pk.y = pk2(accv[it][4 * g + 2], accv[it][4 * g + 3]);
            *(uint2*)(vbb + it * 32 + 8 * g + 4 * hi) = pk;
        }

    if (wave < 4) {
        __hip_bfloat16* T = TqB + wave * (32 * 40);
        #pragma unroll
        for (int r = 0; r < 16; r++) {
            int n = (r & 3) + 8 * (r >> 2) + 4 * hi;
            T[n * 40 + lo] = __float2bfloat16(accq[r]);
        }
    }
    __syncthreads();
    if (wave < 4) {
        __hip_bfloat16* T = TqB + wave * (32 * 40);
        __hip_bfloat16* dst = ((wave < 2) ? qT : kT) + ((size_t)b << 17)
                              + (size_t)(n0 + qk_it * 32) * 32;
        #pragma unroll
        for (int p = 0; p < 2; p++) {
            int idx = p * 64 + lane;
            int n = idx >> 2, quad = idx & 3;
            bf16x8 row = *(const bf16x8*)&T[n * 40 + quad * 8];
            *(bf16x8*)(dst + (size_t)n * 32 + quad * 8) = row;
        }
    }
}

// ---------------------------------------------------------------------------
// attn_part: R15 loop + early V (va0b) loads per phase. 256 thr, grid 1024.
// ---------------------------------------------------------------------------
__global__ __launch_bounds__(256) void attn_part(const __hip_bfloat16* __restrict__ qT,
                                                 const __hip_bfloat16* __restrict__ kT,
                                                 const __hip_bfloat16* __restrict__ v,
                                                 const float* __restrict__ scal,
                                                 __hip_bfloat16* __restrict__ Opart,
                                                 float* __restrict__ Lsum) {
    __shared__ __hip_bfloat16 Plds0[64 * 72];
    __shared__ __hip_bfloat16 Plds1[64 * 72];
    __shared__ float Lp[4][32];

    int t = threadIdx.x;
    int wave = t >> 6, lane = t & 63;
    int lo = lane & 31, hi = lane >> 5;

    int blk = blockIdx.x;
    int x8 = blk & 7;
    int b = x8 >> 1;
    int nq = (blk >> 3) & 3;
    int m0 = (((x8 & 1) << 5) + (blk >> 5)) << 6;
    int nbase = nq << 10;

    const __hip_bfloat16* qTb = qT + ((size_t)b << 17);
    const __hip_bfloat16* kTb = kT + ((size_t)b << 17);
    const __hip_bfloat16* vb  = v  + ((size_t)b << 20);

    int mtile_s = wave >> 1, ntile_s = wave & 1;
    int e0w = wave << 6;
    float qkscale = scal[0] * scal[1] * 0.17677669529663687f;

    bf16x8 qf0 = *(const bf16x8*)(qTb + ((size_t)(m0 + mtile_s * 32 + lo)) * 32 + 0  + hi * 8);
    bf16x8 qf1 = *(const bf16x8*)(qTb + ((size_t)(m0 + mtile_s * 32 + lo)) * 32 + 16 + hi * 8);

    f32x16 acc[2][2];
    #pragma unroll
    for (int et = 0; et < 2; et++)
        #pragma unroll
        for (int mt = 0; mt < 2; mt++)
            #pragma unroll
            for (int r = 0; r < 16; r++) acc[et][mt][r] = 0.f;
    float l_acc = 0.f;

    const __hip_bfloat16* krow0 = kTb + (size_t)(ntile_s * 32 + lo) * 32 + hi * 8;
    const __hip_bfloat16* va0b = vb + (size_t)(e0w + lo) * NPOS + hi * 8;
    const __hip_bfloat16* va1b = vb + (size_t)(e0w + 32 + lo) * NPOS + hi * 8;
    int mrow = mtile_s * 32 + lo;
    int nloc0 = ntile_s * 32 + 4 * hi;

    bf16x8 kfA0, kfA1, kfB0, kfB1;
    {
        const __hip_bfloat16* ka = krow0 + (size_t)nbase * 32;
        kfA0 = *(const bf16x8*)(ka);
        kfA1 = *(const bf16x8*)(ka + 16);
    }

    for (int ss = 0; ss < 8; ss++) {
        int n0 = nbase + 128 * ss;

        // phase A
        {
            f32x16 sv;
            #pragma unroll
            for (int r = 0; r < 16; r++) sv[r] = 0.f;
            sv = __builtin_amdgcn_mfma_f32_32x32x16_bf16(kfA0, qf0, sv, 0, 0, 0);
            sv = __builtin_amdgcn_mfma_f32_32x32x16_bf16(kfA1, qf1, sv, 0, 0, 0);

            const __hip_bfloat16* ka = krow0 + (size_t)(n0 + 64) * 32;
            kfB0 = *(const bf16x8*)(ka);
            kfB1 = *(const bf16x8*)(ka + 16);

            // early V loads (row e0w+lo) — latency hides under exp+pack+barrier
            bf16x8 vp0 = *(const bf16x8*)(va0b + n0 + 0);
            bf16x8 vp1 = *(const bf16x8*)(va0b + n0 + 16);
            bf16x8 vp2 = *(const bf16x8*)(va0b + n0 + 32);
            bf16x8 vp3 = *(const bf16x8*)(va0b + n0 + 48);

            #pragma unroll
            for (int g = 0; g < 4; g++) {
                float p0 = __expf(sv[4 * g + 0] * qkscale);
                float p1 = __expf(sv[4 * g + 1] * qkscale);
                float p2 = __expf(sv[4 * g + 2] * qkscale);
                float p3 = __expf(sv[4 * g + 3] * qkscale);
                l_acc += (p0 + p1) + (p2 + p3);
                uint2 pk;
                pk.x = pk2(p0, p1);
                pk.y = pk2(p2, p3);
                *(uint2*)(&Plds0[mrow * 72 + nloc0 + 8 * g]) = pk;
            }
            __syncthreads();

            #pragma unroll
            for (int kc = 0; kc < 4; kc++) {
                bf16x8 pf0 = *(const bf16x8*)(&Plds0[(lo)      * 72 + kc * 16 + hi * 8]);
                bf16x8 pf1 = *(const bf16x8*)(&Plds0[(32 + lo) * 72 + kc * 16 + hi * 8]);
                bf16x8 vf0 = (kc == 0) ? vp0 : (kc == 1) ? vp1 : (kc == 2) ? vp2 : vp3;
                bf16x8 vf1 = *(const bf16x8*)(va1b + n0 + kc * 16);
                acc[0][0] = __builtin_amdgcn_mfma_f32_32x32x16_bf16(vf0, pf0, acc[0][0], 0, 0, 0);
                acc[0][1] = __builtin_amdgcn_mfma_f32_32x32x16_bf16(vf0, pf1, acc[0][1], 0, 0, 0);
                acc[1][0] = __builtin_amdgcn_mfma_f32_32x32x16_bf16(vf1, pf0, acc[1][0], 0, 0, 0);
                acc[1][1] = __builtin_amdgcn_mfma_f32_32x32x16_bf16(vf1, pf1, acc[1][1], 0, 0, 0);
            }
        }

        // phase B
        {
            int n1 = n0 + 64;
            f32x16 sv;
            #pragma unroll
            for (int r = 0; r < 16; r++) sv[r] = 0.f;
            sv = __builtin_amdgcn_mfma_f32_32x32x16_bf16(kfB0, qf0, sv, 0, 0, 0);
            sv = __builtin_amdgcn_mfma_f32_32x32x16_bf16(kfB1, qf1, sv, 0, 0, 0);

            if (ss < 7) {
                const __hip_bfloat16* ka = krow0 + (size_t)(n1 + 64) * 32;
                kfA0 = *(const bf16x8*)(ka);
                kfA1 = *(const bf16x8*)(ka + 16);
            }

            bf16x8 vp0 = *(const bf16x8*)(va0b + n1 + 0);
            bf16x8 vp1 = *(const bf16x8*)(va0b + n1 + 16);
            bf16x8 vp2 = *(const bf16x8*)(va0b + n1 + 32);
            bf16x8 vp3 = *(const bf16x8*)(va0b + n1 + 48);

            #pragma unroll
            for (int g = 0; g < 4; g++) {
                float p0 = __expf(sv[4 * g + 0] * qkscale);
                float p1 = __expf(sv[4 * g + 1] * qkscale);
                float p2 = __expf(sv[4 * g + 2] * qkscale);
                float p3 = __expf(sv[4 * g + 3] * qkscale);
                l_acc += (p0 + p1) + (p2 + p3);
                uint2 pk;
                pk.x = pk2(p0, p1);
                pk.y = pk2(p2, p3);
                *(uint2*)(&Plds1[mrow * 72 + nloc0 + 8 * g]) = pk;
            }
            __syncthreads();

            #pragma unroll
            for (int kc = 0; kc < 4; kc++) {
                bf16x8 pf0 = *(const bf16x8*)(&Plds1[(lo)      * 72 + kc * 16 + hi * 8]);
                bf16x8 pf1 = *(const bf16x8*)(&Plds1[(32 + lo) * 72 + kc * 16 + hi * 8]);
                bf16x8 vf0 = (kc == 0) ? vp0 : (kc == 1) ? vp1 : (kc == 2) ? vp2 : vp3;
                bf16x8 vf1 = *(const bf16x8*)(va1b + n1 + kc * 16);
                acc[0][0] = __builtin_amdgcn_mfma_f32_32x32x16_bf16(vf0, pf0, acc[0][0], 0, 0, 0);
                acc[0][1] = __builtin_amdgcn_mfma_f32_32x32x16_bf16(vf0, pf1, acc[0][1], 0, 0, 0);
                acc[1][0] = __builtin_amdgcn_mfma_f32_32x32x16_bf16(vf1, pf0, acc[1][0], 0, 0, 0);
                acc[1][1] = __builtin_amdgcn_mfma_f32_32x32x16_bf16(vf1, pf1, acc[1][1], 0, 0, 0);
            }
        }
    }

    float lsum = l_acc + __shfl_xor(l_acc, 32, 64);
    if (lane < 32) Lp[wave][lane] = lsum;
    __syncthreads();
    if (wave == 0) {
        int l2 = lane & 31;
        float Lv = (lane < 32) ? (Lp[0][l2] + Lp[1][l2]) : (Lp[2][l2] + Lp[3][l2]);
        Lsum[(size_t)(nq * 4 + b) * NPOS + m0 + ((lane >> 5) << 5) + l2] = Lv;
    }

    __hip_bfloat16* Ob = Opart + ((size_t)(nq * 4 + b) << 20);
    #pragma unroll
    for (int mt = 0; mt < 2; mt++) {
        int m = m0 + mt * 32 + lo;
        #pragma unroll
        for (int et = 0; et < 2; et++) {
            #pragma unroll
            for (int r = 0; r < 16; r++) {
                int e = e0w + et * 32 + (r & 3) + 8 * (r >> 2) + 4 * hi;
                Ob[(size_t)e * NPOS + m] = __float2bfloat16(acc[et][mt][r]);
            }
        }
    }
}

// ---------------------------------------------------------------------------
// reduce_out: out = x + gamma*sig_v^-1 * (sum_q Oq)/(sum_q Lq).
// grid (2, 256, 4) x 256 thr; 8 floats/thread. (R15 verbatim)
// ---------------------------------------------------------------------------
__global__ __launch_bounds__(256) void reduce_out(const float* __restrict__ x,
                                                  const __hip_bfloat16* __restrict__ Opart,
                                                  const float* __restrict__ Lsum,
                                                  const float* __restrict__ scal,
                                                  const float* __restrict__ gam,
                                                  float* __restrict__ out) {
    int b = blockIdx.z, e = blockIdx.y;
    int m8 = (blockIdx.x * 256 + threadIdx.x) * 8;
    float gs = gam[0] * scal[2];

    size_t o = ((size_t)b << 20) + (size_t)e * NPOS + m8;
    float4 xv0 = *(const float4*)(x + o);
    float4 xv1 = *(const float4*)(x + o + 4);

    float os[8] = {0, 0, 0, 0, 0, 0, 0, 0};
    float ls[8] = {0, 0, 0, 0, 0, 0, 0, 0};
    #pragma unroll
    for (int q = 0; q < 4; q++) {
        int sl = q * 4 + b;
        const ushort* ap = (const ushort*)(Opart + ((size_t)sl << 20) + (size_t)e * NPOS + m8);
        ushort4 a0 = *(const ushort4*)ap;
        ushort4 a1 = *(const ushort4*)(ap + 4);
        float4 L0 = *(const float4*)(Lsum + (size_t)sl * NPOS + m8);
        float4 L1 = *(const float4*)(Lsum + (size_t)sl * NPOS + m8 + 4);
        os[0] += b2f(a0.x); os[1] += b2f(a0.y); os[2] += b2f(a0.z); os[3] += b2f(a0.w);
        os[4] += b2f(a1.x); os[5] += b2f(a1.y); os[6] += b2f(a1.z); os[7] += b2f(a1.w);
        ls[0] += L0.x; ls[1] += L0.y; ls[2] += L0.z; ls[3] += L0.w;
        ls[4] += L1.x; ls[5] += L1.y; ls[6] += L1.z; ls[7] += L1.w;
    }

    float4 r0, r1;
    r0.x = xv0.x + gs * os[0] / ls[0];
    r0.y = xv0.y + gs * os[1] / ls[1];
    r0.z = xv0.z + gs * os[2] / ls[2];
    r0.w = xv0.w + gs * os[3] / ls[3];
    r1.x = xv1.x + gs * os[4] / ls[4];
    r1.y = xv1.y + gs * os[5] / ls[5];
    r1.z = xv1.z + gs * os[6] / ls[6];
    r1.w = xv1.w + gs * os[7] / ls[7];
    *(float4*)(out + o) = r0;
    *(float4*)(out + o + 4) = r1;
}

// ---------------------------------------------------------------------------
extern "C" void kernel_launch(void* const* d_in, const int* in_sizes, int n_in,
                              void* d_out, int out_size, void* d_ws, size_t ws_size,
                              hipStream_t stream) {
    const float* x     = (const float*)d_in[0];
    const float* wq    = (const float*)d_in[1];
    const float* wk    = (const float*)d_in[2];
    const float* wv    = (const float*)d_in[3];
    const float* gamma = (const float*)d_in[4];
    float* out = (float*)d_out;

    char* wsb = (char*)d_ws;
    float* scal = (float*)wsb;                           // 256 B
    __hip_bfloat16* qT = (__hip_bfloat16*)(wsb + 256);   // 1 MB
    __hip_bfloat16* kT = qT + ((size_t)4 << 17);         // 1 MB
    __hip_bfloat16* vp = kT + ((size_t)4 << 17);         // 8 MB
    __hip_bfloat16* Opart = vp + ((size_t)4 << 20);      // 32 MB (16 slices x 2MB)
    float* Lsum = (float*)(Opart + ((size_t)16 << 20));  // 256 KB

    proj_sigma<<<dim3(65, 4), 512, 0, stream>>>(x, wq, wk, wv, qT, kT, vp, scal);
    attn_part<<<1024, 256, 0, stream>>>(qT, kT, vp, scal, Opart, Lsum);
    reduce_out<<<dim3(2, 256, 4), 256, 0, stream>>>(x, Opart, Lsum, scal, gamma, out);
}